// Round 3
// baseline (1956.106 us; speedup 1.0000x reference)
//
#include <hip/hip_runtime.h>
#include <hip/hip_fp16.h>

// Literal replication of the reference:
//   X = rfft(x, n=163839); H = rfft(h, n=163839); y = irfft(X*H)[:131072]
// N1=163839 (3*13*4201), N2=163838 (2*81919, 81919 prime) -> Bluestein on L=2^18.
// Four-step 512x512 FFT in permuted layout (no transposes).
// R2 fix: CM_COMBINE now performs the missing inverse column FFT (completing
// X's Bluestein conv) before the pointwise product, then the forward column
// FFT of the inverse-chirp transform. R1 had fused away that FFT -> garbage X.

#define L1FFT 262144
#define NCHAN 128
#define CN1 163839LL
#define CN2 163838LL
#define MBINS 81920
#define XLEN 131072
#define HLEN 32768
#define PI_F 3.14159265358979323846f

#define CM_BUILD   0
#define CM_REAL    1
#define CM_COMBINE 2
#define CM_EXTRACT 3
#define CM_FINAL   4
#define RM_BUILD   0
#define RM_CONV    1

__device__ __forceinline__ float2 cmulf(float2 a, float2 b) {
  return make_float2(a.x*b.x - a.y*b.y, a.x*b.y + a.y*b.x);
}
__device__ __forceinline__ float2 caddf(float2 a, float2 b){ return make_float2(a.x+b.x, a.y+b.y); }
__device__ __forceinline__ float2 csubf(float2 a, float2 b){ return make_float2(a.x-b.x, a.y-b.y); }

// e^{sgn * i*pi*n^2 / Q}, phase reduced exactly via integer mod (n^2 mod 2Q)
__device__ __forceinline__ float2 chirpv(float sgn, long long Q, long long n) {
  long long m = (n*n) % (2*Q);
  float ang = sgn * PI_F * (float)m / (float)Q;
  float s, c; __sincosf(ang, &s, &c);
  return make_float2(c, s);
}

// In-LDS 512-point complex FFT, 32 lanes per FFT (d = row base, contiguous 512 float2).
// dsg = -1 forward, +1 inverse (both unnormalized).
// bitrev(9) + radix-2 + 4x radix-4 with bitrev sub-block order (0,2,1,3).
__device__ __forceinline__ void fft512(float2* d, int l, float dsg) {
  #pragma unroll
  for (int i = 0; i < 16; ++i) {
    int idx = l + 32*i;
    int r = __brev((unsigned)idx) >> 23;
    if (r > idx) { float2 t0 = d[idx]; d[idx] = d[r]; d[r] = t0; }
  }
  __syncthreads();
  #pragma unroll
  for (int i = 0; i < 8; ++i) {
    int i0 = (l + 32*i) * 2;
    float2 a = d[i0], b = d[i0+1];
    d[i0] = caddf(a,b); d[i0+1] = csubf(a,b);
  }
  __syncthreads();
  #pragma unroll
  for (int st = 0; st < 4; ++st) {
    const int lq = 1 + 2*st;
    const int q = 1 << lq;
    const int estep = 512 >> (lq + 2);
    const float base = dsg * (2.0f * PI_F / 512.0f);
    #pragma unroll
    for (int uu = 0; uu < 4; ++uu) {
      int u = l + 32*uu;
      int j = u & (q-1);
      int g = u >> lq;
      int i0 = (g << (lq+2)) + j;
      float ang = base * (float)(j * estep);
      float s1, c1; __sincosf(ang, &s1, &c1);
      float2 w1 = make_float2(c1, s1);
      float2 w2 = cmulf(w1, w1);
      float2 w3 = cmulf(w2, w1);
      float2 a0 = d[i0];
      float2 a2 = cmulf(d[i0 +   q], w2);   // offset q holds residue 2
      float2 a1 = cmulf(d[i0 + 2*q], w1);   // offset 2q holds residue 1
      float2 a3 = cmulf(d[i0 + 3*q], w3);
      float2 s02 = caddf(a0, a2), d02 = csubf(a0, a2);
      float2 s13 = caddf(a1, a3), d13 = csubf(a1, a3);
      float2 jd = (dsg < 0.f) ? make_float2(d13.y, -d13.x)
                              : make_float2(-d13.y, d13.x);
      d[i0]       = caddf(s02, s13);
      d[i0 +   q] = caddf(d02, jd);
      d[i0 + 2*q] = csubf(s02, s13);
      d[i0 + 3*q] = csubf(d02, jd);
    }
    __syncthreads();
  }
}

// Column-type pass: 8 columns per block; FFT over r (the stride-512 dimension).
// BUILD/REAL: build/load real values, fwd FFT, four-step twiddle, full store.
// EXTRACT:    complex load, inv FFT (completes Bluestein), post-chirp, half2 store.
// FINAL:      complex load, inv FFT, post-chirp, Re, f32 store.
// COMBINE:    complex load, inv FFT (completes X Bluestein), pointwise
//             (postchirp_N1 * Hc * eps/N2 * prechirp_N2), fwd FFT, twiddle, store.
// In-place (cplxSrc == dstFull) is safe: block reads exactly the element set it
// writes, and all global reads land in LDS before any global store.
__global__ __launch_bounds__(256) void pass_col_k(
    int mode,
    const float* __restrict__ realSrc, int realLen,
    const float2* cplxSrc,
    const __half2* __restrict__ hcIn,
    float2* dstFull,
    __half2* __restrict__ specOut,
    float* __restrict__ realOut,
    long long Q, float csgn, int lo, int hi)
{
  __shared__ float2 tile[8 * 512];   // 32 KiB
  const int t  = threadIdx.x;
  const int c0 = blockIdx.x * 8;
  const int ch = blockIdx.y;         // chunk-local channel

  #pragma unroll
  for (int i = 0; i < 16; ++i) {
    int qq = t + 256*i;
    int cc = qq & 7, r = qq >> 3;
    int n = (r << 9) + c0 + cc;
    float2 v = make_float2(0.f, 0.f);
    if (mode == CM_BUILD) {
      int np = (n <= hi) ? n : n - L1FFT;
      if (np >= lo) v = chirpv(csgn, Q, (long long)np);
    } else if (mode == CM_REAL) {
      if (n < realLen) {
        float xv = realSrc[(size_t)ch * realLen + n];
        float2 cw = chirpv(-1.f, CN1, (long long)n);   // pre-chirp e^{-i pi n^2/N1}
        v = make_float2(xv * cw.x, xv * cw.y);
      }
    } else {  // COMBINE / EXTRACT / FINAL: plain complex load
      v = cplxSrc[(size_t)ch * L1FFT + n];
    }
    tile[cc * 512 + r] = v;
  }
  __syncthreads();

  // BUILD/REAL: forward.  COMBINE/EXTRACT/FINAL: inverse (completes a Bluestein conv).
  const float dsg1 = (mode <= CM_REAL) ? -1.f : 1.f;
  fft512(tile + (t >> 5) * 512, t & 31, dsg1);

  if (mode == CM_COMBINE) {
    // tile[cc][r] now holds conv result b[k], k = r*512 + (c0+cc) — X's Bluestein
    // output. Pointwise product with H spectrum, then start the inverse-chirp
    // transform with a forward FFT over the same (stride-512) digit.
    #pragma unroll
    for (int i = 0; i < 16; ++i) {
      int qq = t + 256*i;
      int cc = qq & 7, r = qq >> 3;
      int k = (r << 9) + c0 + cc;
      float2 v = make_float2(0.f, 0.f);
      if (k < MBINS) {
        float2 X = cmulf(tile[cc * 512 + r], chirpv(-1.f, CN1, (long long)k));
        float2 H = __half22float2(hcIn[(size_t)ch * MBINS + k]);
        float2 Y = cmulf(X, H);
        float eps = (k == 0 || k == MBINS - 1) ? 1.0f : 2.0f;  // c2r bin weights
        float sc = eps / (float)CN2;                            // fold 1/N2
        v = cmulf(make_float2(Y.x * sc, Y.y * sc), chirpv(+1.f, CN2, (long long)k));
      }
      tile[cc * 512 + r] = v;
    }
    __syncthreads();
    fft512(tile + (t >> 5) * 512, t & 31, -1.f);
  }

  #pragma unroll
  for (int i = 0; i < 16; ++i) {
    int qq = t + 256*i;
    int cc = qq & 7, r = qq >> 3;    // r = k1 (fwd modes) or n2 (inv modes)
    float2 v = tile[cc * 512 + r];
    int c = c0 + cc;
    int n = (r << 9) + c;
    if (mode <= CM_COMBINE) {
      float ang = -(2.0f * PI_F / (float)L1FFT) * (float)(c * r);  // W_L^{c*k1}
      float s1, c1; __sincosf(ang, &s1, &c1);
      v = cmulf(v, make_float2(c1, s1));
      dstFull[(size_t)ch * L1FFT + n] = v;
    } else if (mode == CM_EXTRACT) {
      if (n < MBINS) {
        float2 cw = chirpv(-1.f, CN1, (long long)n);   // post-chirp e^{-i pi k^2/N1}
        specOut[(size_t)ch * MBINS + n] = __float22half2_rn(cmulf(v, cw));
      }
    } else { // CM_FINAL
      if (n < XLEN) {
        float2 cw = chirpv(+1.f, CN2, (long long)n);   // e^{+i pi t^2/N2}, take Re
        realOut[(size_t)ch * XLEN + n] = v.x * cw.x - v.y * cw.y;
      }
    }
  }
}

// Row-type pass: 8 contiguous rows of 512 per block.
// RM_BUILD: fwd FFT only (completes chirp-kernel spectrum, permuted layout), store.
// RM_CONV: fwd FFT, * G, inv FFT, conj four-step twiddle * 1/L, store in place.
__global__ __launch_bounds__(256) void pass_row_k(
    int mode, float2* a, const float2* __restrict__ g)
{
  __shared__ float2 tile[8 * 512];   // 32 KiB
  const int t  = threadIdx.x;
  const int r0 = blockIdx.x * 8;
  const int ch = blockIdx.y;
  float2* A = a + (size_t)ch * L1FFT;

  #pragma unroll
  for (int i = 0; i < 16; ++i) {
    int qq = t + 256*i;
    int k2 = qq & 511, rr = qq >> 9;
    tile[rr * 512 + k2] = A[(size_t)(r0 + rr) * 512 + k2];
  }
  __syncthreads();
  fft512(tile + (t >> 5) * 512, t & 31, -1.f);

  if (mode == RM_CONV) {
    #pragma unroll
    for (int i = 0; i < 16; ++i) {
      int qq = t + 256*i;
      int k2 = qq & 511, rr = qq >> 9;
      tile[rr * 512 + k2] = cmulf(tile[rr * 512 + k2],
                                  g[(size_t)(r0 + rr) * 512 + k2]);
    }
    __syncthreads();
    fft512(tile + (t >> 5) * 512, t & 31, +1.f);
    #pragma unroll
    for (int i = 0; i < 16; ++i) {
      int qq = t + 256*i;
      int c = qq & 511, rr = qq >> 9;
      float2 v = tile[rr * 512 + c];
      float ang = (2.0f * PI_F / (float)L1FFT) * (float)(c * (r0 + rr)); // conj twiddle
      float s1, c1; __sincosf(ang, &s1, &c1);
      v = cmulf(v, make_float2(c1, s1));
      v.x *= (1.0f / (float)L1FFT);
      v.y *= (1.0f / (float)L1FFT);
      A[(size_t)(r0 + rr) * 512 + c] = v;
    }
  } else {
    #pragma unroll
    for (int i = 0; i < 16; ++i) {
      int qq = t + 256*i;
      int k2 = qq & 511, rr = qq >> 9;
      A[(size_t)(r0 + rr) * 512 + k2] = tile[rr * 512 + k2];
    }
  }
}

// Diagnostic: distinguishable absmax signature if workspace is too small.
__global__ void diag_ws_too_small(float* out) { out[0] = 123456.0f; }

extern "C" void kernel_launch(void* const* d_in, const int* in_sizes, int n_in,
                              void* d_out, int out_size, void* d_ws, size_t ws_size,
                              hipStream_t stream) {
  const float* x = (const float*)d_in[0];   // (32,4,131072) f32
  const float* h = (const float*)d_in[1];   // (32,4,32768)  f32
  float* out = (float*)d_out;

  // ws layout: V1 (2 MiB) | W (2 MiB) | A (chunk * 2 MiB) | Hc (chunk * 0.3125 MiB)
  const size_t fixedB   = 2ull * L1FFT * sizeof(float2);
  const size_t perChanB = (size_t)L1FFT * sizeof(float2) + (size_t)MBINS * sizeof(__half2);
  if (ws_size < fixedB + perChanB) {
    diag_ws_too_small<<<1, 1, 0, stream>>>(out);
    return;
  }
  int chunk = (int)((ws_size - fixedB) / perChanB);
  if (chunk > NCHAN) chunk = NCHAN;

  float2*  V1 = (float2*)d_ws;
  float2*  W  = V1 + L1FFT;
  float2*  A  = W + L1FFT;
  __half2* Hc = (__half2*)(A + (size_t)chunk * L1FFT);

  dim3 blk(256);
  dim3 g1(64, 1);

  // --- chirp-kernel spectra (channel-independent, rebuilt every call) ---
  // V1: v(n) = e^{+i pi n^2/N1}, support n in [-(XLEN-1), MBINS-1]
  pass_col_k<<<g1, blk, 0, stream>>>(CM_BUILD, nullptr, 0, nullptr, nullptr,
                                     V1, nullptr, nullptr, CN1, +1.f, -(XLEN-1), MBINS-1);
  pass_row_k<<<g1, blk, 0, stream>>>(RM_BUILD, V1, nullptr);
  // W: w(n) = e^{-i pi n^2/N2}, support n in [-(MBINS-1), XLEN-1]
  pass_col_k<<<g1, blk, 0, stream>>>(CM_BUILD, nullptr, 0, nullptr, nullptr,
                                     W, nullptr, nullptr, CN2, -1.f, -(MBINS-1), XLEN-1);
  pass_row_k<<<g1, blk, 0, stream>>>(RM_BUILD, W, nullptr);

  for (int ch0 = 0; ch0 < NCHAN; ch0 += chunk) {
    int nc = NCHAN - ch0; if (nc > chunk) nc = chunk;
    dim3 gC(64, nc);
    const float* hq = h   + (size_t)ch0 * HLEN;
    const float* xq = x   + (size_t)ch0 * XLEN;
    float*       oq = out + (size_t)ch0 * XLEN;

    // H[k] = DFT_N1(h)[k] -> Hc (half2): full Bluestein (col, row, inv-col)
    pass_col_k<<<gC, blk, 0, stream>>>(CM_REAL, hq, HLEN, nullptr, nullptr,
                                       A, nullptr, nullptr, CN1, 0.f, 0, 0);
    pass_row_k<<<gC, blk, 0, stream>>>(RM_CONV, A, V1);
    pass_col_k<<<gC, blk, 0, stream>>>(CM_EXTRACT, nullptr, 0, A, nullptr,
                                       nullptr, Hc, nullptr, CN1, 0.f, 0, 0);

    // X path: col + row of Bluestein conv; COMBINE completes the inverse
    // col FFT, multiplies, and starts the inverse-chirp transform.
    pass_col_k<<<gC, blk, 0, stream>>>(CM_REAL, xq, XLEN, nullptr, nullptr,
                                       A, nullptr, nullptr, CN1, 0.f, 0, 0);
    pass_row_k<<<gC, blk, 0, stream>>>(RM_CONV, A, V1);
    pass_col_k<<<gC, blk, 0, stream>>>(CM_COMBINE, nullptr, 0, A, Hc,
                                       A, nullptr, nullptr, CN2, 0.f, 0, 0);
    // conv with W, then post-chirp + Re -> out
    pass_row_k<<<gC, blk, 0, stream>>>(RM_CONV, A, W);
    pass_col_k<<<gC, blk, 0, stream>>>(CM_FINAL, nullptr, 0, A, nullptr,
                                       nullptr, nullptr, oq, CN2, 0.f, 0, 0);
  }
}

// Round 4
// 1332.653 us; speedup vs baseline: 1.4678x; 1.4678x over previous
//
#include <hip/hip_runtime.h>
#include <hip/hip_fp16.h>

// Literal replication of the reference:
//   X = rfft(x, n=163839); H = rfft(h, n=163839); y = irfft(X*H)[:131072]
// N1=163839, N2=163838 -> Bluestein on L=2^18; four-step 512x512.
// R3: register+shuffle FFT-512 (16 pts/lane, cross-lane via shfl_xor),
// LDS only for layout conversion (bank-floor verified maps, stride 514),
// row passes LDS-free (spectra stored in FFT-state order), Hc in [c][n] layout.

#define L1FFT 262144
#define NCHAN 128
#define CN1 163839LL
#define CN2 163838LL
#define MBINS 81920
#define XLEN 131072
#define HLEN 32768
#define TWO_PI 6.28318530717958647692f

#define CM_BUILD   0
#define CM_REAL    1
#define CM_COMBINE 2
#define CM_EXTRACT 3
#define CM_FINAL   4
#define RM_BUILD   0
#define RM_CONV    1

#define TSTRIDE 514   // float2 tile row stride: 2*514 mod 32 == 4 -> bank-floor maps

__device__ __forceinline__ float2 cmulf(float2 a, float2 b) {
  return make_float2(a.x*b.x - a.y*b.y, a.x*b.y + a.y*b.x);
}
__device__ __forceinline__ float2 caddf(float2 a, float2 b){ return make_float2(a.x+b.x, a.y+b.y); }
__device__ __forceinline__ float2 csubf(float2 a, float2 b){ return make_float2(a.x-b.x, a.y-b.y); }

// e^{sgn * i*pi*n^2 / Q}, phase reduced exactly via integer mod (n^2 mod 2Q)
__device__ __forceinline__ float2 chirpv(float sgn, long long Q, long long n) {
  long long m = (n*n) % (2*Q);
  float ang = sgn * (0.5f*TWO_PI) * (float)m / (float)Q;
  float s, c; __sincosf(ang, &s, &c);
  return make_float2(c, s);
}

__device__ __forceinline__ int brev4(int x) {
  return ((x&1)<<3) | ((x&2)<<1) | ((x&4)>>1) | ((x&8)>>3);
}
__device__ __forceinline__ int brev5(int x) {
  return (int)(__brev((unsigned)x) >> 27);
}
__device__ __forceinline__ float2 shflx(float2 a, int m) {
  return make_float2(__shfl_xor(a.x, m, 64), __shfl_xor(a.y, m, 64));
}

#define C16_0 1.f
#define C16_1 0.9238795325f
#define C16_2 0.7071067812f
#define C16_3 0.3826834324f
__device__ __forceinline__ float c16t(int j) {
  const float C[8] = {C16_0, C16_1, C16_2, C16_3, 0.f, -C16_3, -C16_2, -C16_1};
  return C[j];
}
__device__ __forceinline__ float s16t(int j) {
  const float S[8] = {0.f, C16_3, C16_2, C16_1, 1.f, C16_1, C16_2, C16_3};
  return S[j];
}

// ---- in-lane 16-point DIF (forward, sign dsg): v[p] ends as F[brev4(p)] ----
__device__ __forceinline__ void lane16_fwd(float2 v[16], float dsg) {
  #pragma unroll
  for (int j = 0; j < 8; ++j) {               // stage0: (j, j+8), W16^j
    float wr = c16t(j), wi = dsg * s16t(j);
    float2 a = v[j], b = v[j+8];
    v[j] = caddf(a, b);
    float2 tt = csubf(a, b);
    v[j+8] = make_float2(tt.x*wr - tt.y*wi, tt.x*wi + tt.y*wr);
  }
  #pragma unroll
  for (int h = 0; h < 2; ++h)                 // stage1: (b+j, b+j+4), W16^{2j}
    #pragma unroll
    for (int j = 0; j < 4; ++j) {
      int i0 = h*8 + j;
      float wr = c16t(2*j), wi = dsg * s16t(2*j);
      float2 a = v[i0], b = v[i0+4];
      v[i0] = caddf(a, b);
      float2 tt = csubf(a, b);
      v[i0+4] = make_float2(tt.x*wr - tt.y*wi, tt.x*wi + tt.y*wr);
    }
  #pragma unroll
  for (int q = 0; q < 4; ++q)                 // stage2: (b+j, b+j+2), W16^{4j}
    #pragma unroll
    for (int j = 0; j < 2; ++j) {
      int i0 = q*4 + j;
      float2 a = v[i0], b = v[i0+2];
      v[i0] = caddf(a, b);
      float2 tt = csubf(a, b);
      v[i0+2] = (j == 0) ? tt : make_float2(-dsg*tt.y, dsg*tt.x); // *(0,dsg)
    }
  #pragma unroll
  for (int p = 0; p < 8; ++p) {               // stage3: pairs, W=1
    float2 a = v[2*p], b = v[2*p+1];
    v[2*p] = caddf(a, b);
    v[2*p+1] = csubf(a, b);
  }
}

// ---- in-lane 16-point inverse-mirror (input in fwd-output order, x512/16 gain) ----
__device__ __forceinline__ void lane16_inv(float2 v[16], float dsg) {
  #pragma unroll
  for (int p = 0; p < 8; ++p) {               // stage3'
    float2 a = v[2*p], b = v[2*p+1];
    v[2*p] = caddf(a, b);
    v[2*p+1] = csubf(a, b);
  }
  #pragma unroll
  for (int q = 0; q < 4; ++q)                 // stage2': conj(W16^{4j})
    #pragma unroll
    for (int j = 0; j < 2; ++j) {
      int i0 = q*4 + j;
      float2 a = v[i0], b = v[i0+2];
      float2 tb = (j == 0) ? b : make_float2(dsg*b.y, -dsg*b.x); // b*(0,-dsg)
      v[i0] = caddf(a, tb);
      v[i0+2] = csubf(a, tb);
    }
  #pragma unroll
  for (int h = 0; h < 2; ++h)                 // stage1': conj(W16^{2j})
    #pragma unroll
    for (int j = 0; j < 4; ++j) {
      int i0 = h*8 + j;
      float wr = c16t(2*j), wi = dsg * s16t(2*j);
      float2 a = v[i0], b = v[i0+4];
      float2 tb = make_float2(b.x*wr + b.y*wi, b.y*wr - b.x*wi);  // b*conj(w)
      v[i0] = caddf(a, tb);
      v[i0+4] = csubf(a, tb);
    }
  #pragma unroll
  for (int j = 0; j < 8; ++j) {               // stage0': conj(W16^j)
    float wr = c16t(j), wi = dsg * s16t(j);
    float2 a = v[j], b = v[j+8];
    float2 tb = make_float2(b.x*wr + b.y*wi, b.y*wr - b.x*wi);
    v[j] = caddf(a, tb);
    v[j+8] = csubf(a, tb);
  }
}

// ---- cross-lane 32-point DIF over lanes (within 32-lane half-wave) ----
#define XFWD_STAGE(mask, w) {                                                  \
    bool hi = (l & (mask)) != 0;                                               \
    _Pragma("unroll")                                                          \
    for (int r = 0; r < 16; ++r) {                                             \
      float2 o = shflx(v[r], (mask));                                          \
      float2 d = hi ? csubf(o, v[r]) : caddf(v[r], o);                         \
      v[r] = hi ? cmulf(d, (w)) : d;                                           \
    } }
#define XFWD_PLAIN(mask) {                                                     \
    bool hi = (l & (mask)) != 0;                                               \
    _Pragma("unroll")                                                          \
    for (int r = 0; r < 16; ++r) {                                             \
      float2 o = shflx(v[r], (mask));                                          \
      v[r] = hi ? csubf(o, v[r]) : caddf(v[r], o);                             \
    } }
#define XINV_STAGE(mask, w) {                                                  \
    bool hi = (l & (mask)) != 0;                                               \
    _Pragma("unroll")                                                          \
    for (int r = 0; r < 16; ++r) {                                             \
      float2 b = hi ? make_float2(v[r].x*(w).x + v[r].y*(w).y,                 \
                                  v[r].y*(w).x - v[r].x*(w).y) : v[r];         \
      float2 o = shflx(b, (mask));                                             \
      v[r] = hi ? csubf(o, b) : caddf(b, o);                                   \
    } }
#define XINV_PLAIN(mask) {                                                     \
    bool hi = (l & (mask)) != 0;                                               \
    _Pragma("unroll")                                                          \
    for (int r = 0; r < 16; ++r) {                                             \
      float2 b = v[r];                                                         \
      float2 o = shflx(b, (mask));                                             \
      v[r] = hi ? csubf(o, b) : caddf(b, o);                                   \
    } }

// Full 512-pt forward (sign dsg): input lane l reg m = x[l+32m];
// output lane l reg r = X[brev4(r) + 16*brev5(l)].
__device__ __forceinline__ void fft512_fwd(float2 v[16], int l, float dsg) {
  lane16_fwd(v, dsg);
  #pragma unroll
  for (int r = 1; r < 16; ++r) {              // step2: W512^{l*k1}, k1=brev4(r)
    float ang = dsg * (TWO_PI/512.f) * (float)(l * brev4(r));
    float s, c; __sincosf(ang, &s, &c);
    v[r] = cmulf(v[r], make_float2(c, s));
  }
  float sA,cA,sB,cB,sC,cC;
  __sincosf(dsg*(TWO_PI/32.f)*(float)(l&15), &sA, &cA);
  __sincosf(dsg*(TWO_PI/16.f)*(float)(l&7),  &sB, &cB);
  __sincosf(dsg*(TWO_PI/8.f) *(float)(l&3),  &sC, &cC);
  float2 wA = make_float2(cA,sA), wB = make_float2(cB,sB), wC = make_float2(cC,sC);
  float2 wD = (l&1) ? make_float2(0.f, dsg) : make_float2(1.f, 0.f);
  XFWD_STAGE(16, wA); XFWD_STAGE(8, wB); XFWD_STAGE(4, wC);
  XFWD_STAGE(2, wD);  XFWD_PLAIN(1);
}

// Unnormalized inverse (x512) of fft512_fwd(dsg): input in fwd-output order,
// output lane l reg m = 512 * x[l+32m]-equivalent = sum_k A[k] e^{-dsg i 2pi kn/512}.
__device__ __forceinline__ void fft512_inv(float2 v[16], int l, float dsg) {
  float sA,cA,sB,cB,sC,cC;
  __sincosf(dsg*(TWO_PI/32.f)*(float)(l&15), &sA, &cA);
  __sincosf(dsg*(TWO_PI/16.f)*(float)(l&7),  &sB, &cB);
  __sincosf(dsg*(TWO_PI/8.f) *(float)(l&3),  &sC, &cC);
  float2 wA = make_float2(cA,sA), wB = make_float2(cB,sB), wC = make_float2(cC,sC);
  float2 wD = (l&1) ? make_float2(0.f, dsg) : make_float2(1.f, 0.f);
  XINV_PLAIN(1); XINV_STAGE(2, wD); XINV_STAGE(4, wC);
  XINV_STAGE(8, wB); XINV_STAGE(16, wA);
  #pragma unroll
  for (int r = 1; r < 16; ++r) {              // step2': conj
    float ang = -dsg * (TWO_PI/512.f) * (float)(l * brev4(r));
    float s, c; __sincosf(ang, &s, &c);
    v[r] = cmulf(v[r], make_float2(c, s));
  }
  lane16_inv(v, dsg);
}

// ---------------- column pass ----------------
// FFT over the stride-512 digit. 8 columns/block; half-wave (32 lanes) per column.
__global__ __launch_bounds__(256) void pass_col_k(
    int mode,
    const float* __restrict__ realSrc, int realLen,
    const float2* cplxSrc,
    const __half2* __restrict__ hcIn,
    float2* dstFull,
    __half2* __restrict__ specOut,
    float* __restrict__ realOut,
    long long Q, float csgn, int lo, int hi)
{
  __shared__ float2 tile[8 * TSTRIDE];
  const int t   = threadIdx.x;
  const int c0  = blockIdx.x * 8;
  const int ch  = blockIdx.y;
  const int l   = t & 31;
  const int ccf = t >> 5;           // this thread's FFT column (0..7)
  const int c   = c0 + ccf;
  float2 v[16];

  if (mode == CM_BUILD) {
    #pragma unroll
    for (int m = 0; m < 16; ++m) {
      int n = ((l + 32*m) << 9) + c;
      int np = (n <= hi) ? n : n - L1FFT;
      v[m] = (np >= lo) ? chirpv(csgn, Q, (long long)np) : make_float2(0.f, 0.f);
    }
  } else if (mode == CM_REAL) {
    #pragma unroll
    for (int i = 0; i < 16; ++i) {  // (a): coalesced load + prechirp -> natural tile
      int qq = t + 256*i;
      int cc = qq & 7, r = qq >> 3;
      int n = (r << 9) + c0 + cc;
      float2 val = make_float2(0.f, 0.f);
      if (n < realLen) {
        float xv = realSrc[(size_t)ch * realLen + n];
        float2 cw = chirpv(-1.f, CN1, (long long)n);
        val = make_float2(xv*cw.x, xv*cw.y);
      }
      tile[cc*TSTRIDE + r] = val;
    }
    __syncthreads();
    #pragma unroll
    for (int m = 0; m < 16; ++m) v[m] = tile[ccf*TSTRIDE + l + 32*m];
    __syncthreads();
  } else {
    // inverse modes: scatter-load A[j*512+c] into FFT-state order
    #pragma unroll
    for (int i = 0; i < 16; ++i) {
      int qq = t + 256*i;
      int cc = qq & 7, z = qq >> 3;
      int la = z & 31, ra = z >> 5;
      int j = brev4(ra) + 16*brev5(la);
      tile[cc*TSTRIDE + la + 32*ra] = cplxSrc[(size_t)ch*L1FFT + (j << 9) + c0 + cc];
    }
    __syncthreads();
    #pragma unroll
    for (int m = 0; m < 16; ++m) v[m] = tile[ccf*TSTRIDE + l + 32*m];
    __syncthreads();
  }

  if (mode == CM_COMBINE) {
    fft512_inv(v, l, -1.f);         // completes X's Bluestein conv (natural n)
    #pragma unroll
    for (int m = 0; m < 16; ++m) {
      if (m <= 4) {                 // n < 160 <=> k < MBINS (160*512 == 81920)
        int n = l + 32*m;
        long long k = ((long long)n << 9) + c;
        float2 X = cmulf(v[m], chirpv(-1.f, CN1, k));
        float2 H = __half22float2(hcIn[(size_t)ch*MBINS + c*160 + n]);
        float2 Y = cmulf(X, H);
        float eps = (k == 0 || k == MBINS-1) ? 1.f : 2.f;
        float sc = eps / (float)CN2;
        v[m] = cmulf(make_float2(Y.x*sc, Y.y*sc), chirpv(+1.f, CN2, k));
      } else v[m] = make_float2(0.f, 0.f);
    }
  }

  if (mode <= CM_COMBINE) {         // BUILD / REAL / COMBINE: fwd FFT + store
    fft512_fwd(v, l, -1.f);
    #pragma unroll
    for (int r = 0; r < 16; ++r) {  // four-step twiddle + (c) swapped-slot write
      int k1 = brev4(r), k2 = brev5(l);
      int kf = k1 + 16*k2;
      float ang = -(TWO_PI/(float)L1FFT) * (float)(c * kf);
      float s, cs; __sincosf(ang, &s, &cs);
      tile[ccf*TSTRIDE + k2 + 32*k1] = cmulf(v[r], make_float2(cs, s));
    }
    __syncthreads();
    {
      int cc = t & 7, u = t >> 3;   // (d): linear drain, 64B chunks
      #pragma unroll
      for (int i = 0; i < 16; ++i)
        dstFull[(size_t)ch*L1FFT + ((i + 16*u) << 9) + c0 + cc] =
            tile[cc*TSTRIDE + u + 32*i];
    }
  } else if (mode == CM_EXTRACT) {
    fft512_inv(v, l, -1.f);
    #pragma unroll
    for (int m = 0; m <= 4; ++m) {
      int n = l + 32*m;
      long long k = ((long long)n << 9) + c;
      float2 cw = chirpv(-1.f, CN1, k);
      specOut[(size_t)ch*MBINS + c*160 + n] = __float22half2_rn(cmulf(v[m], cw));
    }
  } else {                          // CM_FINAL
    fft512_inv(v, l, -1.f);
    float* tf = (float*)tile;
    #pragma unroll
    for (int m = 0; m < 8; ++m) {   // n < 256 <=> t_out < XLEN (256*512)
      int n = l + 32*m;
      long long nb = ((long long)n << 9) + c;
      float2 cw = chirpv(+1.f, CN2, nb);
      tf[ccf*513 + n] = v[m].x*cw.x - v[m].y*cw.y;
    }
    __syncthreads();
    {
      int cc = t & 7, u = t >> 3;
      #pragma unroll
      for (int i = 0; i < 8; ++i) {
        int n = u + 32*i;
        realOut[(size_t)ch*XLEN + (n << 9) + c0 + cc] = tf[cc*513 + n];
      }
    }
  }
}

// ---------------- row pass (LDS-free) ----------------
// 8 rows/block, half-wave per row. RM_BUILD stores FFT-state order (spectra);
// RM_CONV: fwd, *G (state-aligned), inv, conj four-step twiddle * 1/L, natural store.
__global__ __launch_bounds__(256) void pass_row_k(
    int mode, float2* a, const float2* __restrict__ g)
{
  const int t = threadIdx.x;
  const int l = t & 31;
  const int row = blockIdx.x * 8 + (t >> 5);
  const int ch = blockIdx.y;
  float2* A = a + (size_t)ch * L1FFT + (size_t)row * 512;
  float2 v[16];
  #pragma unroll
  for (int m = 0; m < 16; ++m) v[m] = A[l + 32*m];

  if (mode == RM_CONV) {
    const float2* G = g + (size_t)row * 512;
    float2 gv[16];
    #pragma unroll
    for (int m = 0; m < 16; ++m) gv[m] = G[l + 32*m];
    fft512_fwd(v, l, -1.f);
    #pragma unroll
    for (int r = 0; r < 16; ++r) v[r] = cmulf(v[r], gv[r]);
    fft512_inv(v, l, -1.f);
    #pragma unroll
    for (int m = 0; m < 16; ++m) {
      int cidx = l + 32*m;
      float ang = (TWO_PI/(float)L1FFT) * (float)(cidx * row);
      float s, c_; __sincosf(ang, &s, &c_);
      float2 r_ = cmulf(v[m], make_float2(c_, s));
      A[cidx] = make_float2(r_.x * (1.f/(float)L1FFT), r_.y * (1.f/(float)L1FFT));
    }
  } else {
    fft512_fwd(v, l, -1.f);
    #pragma unroll
    for (int r = 0; r < 16; ++r) A[l + 32*r] = v[r];  // FFT-state order
  }
}

__global__ void diag_ws_too_small(float* out) { out[0] = 123456.0f; }

extern "C" void kernel_launch(void* const* d_in, const int* in_sizes, int n_in,
                              void* d_out, int out_size, void* d_ws, size_t ws_size,
                              hipStream_t stream) {
  const float* x = (const float*)d_in[0];   // (32,4,131072) f32
  const float* h = (const float*)d_in[1];   // (32,4,32768)  f32
  float* out = (float*)d_out;

  const size_t fixedB   = 2ull * L1FFT * sizeof(float2);
  const size_t perChanB = (size_t)L1FFT * sizeof(float2) + (size_t)MBINS * sizeof(__half2);
  if (ws_size < fixedB + perChanB) {
    diag_ws_too_small<<<1, 1, 0, stream>>>(out);
    return;
  }
  int chunk = (int)((ws_size - fixedB) / perChanB);
  if (chunk > NCHAN) chunk = NCHAN;

  float2*  V1 = (float2*)d_ws;
  float2*  W  = V1 + L1FFT;
  float2*  A  = W + L1FFT;
  __half2* Hc = (__half2*)(A + (size_t)chunk * L1FFT);

  dim3 blk(256);
  dim3 g1(64, 1);

  // chirp-kernel spectra (channel-independent)
  pass_col_k<<<g1, blk, 0, stream>>>(CM_BUILD, nullptr, 0, nullptr, nullptr,
                                     V1, nullptr, nullptr, CN1, +1.f, -(XLEN-1), MBINS-1);
  pass_row_k<<<g1, blk, 0, stream>>>(RM_BUILD, V1, nullptr);
  pass_col_k<<<g1, blk, 0, stream>>>(CM_BUILD, nullptr, 0, nullptr, nullptr,
                                     W, nullptr, nullptr, CN2, -1.f, -(MBINS-1), XLEN-1);
  pass_row_k<<<g1, blk, 0, stream>>>(RM_BUILD, W, nullptr);

  for (int ch0 = 0; ch0 < NCHAN; ch0 += chunk) {
    int nc = NCHAN - ch0; if (nc > chunk) nc = chunk;
    dim3 gC(64, nc);
    const float* hq = h   + (size_t)ch0 * HLEN;
    const float* xq = x   + (size_t)ch0 * XLEN;
    float*       oq = out + (size_t)ch0 * XLEN;

    // H[k] -> Hc ([c][n] layout, half2)
    pass_col_k<<<gC, blk, 0, stream>>>(CM_REAL, hq, HLEN, nullptr, nullptr,
                                       A, nullptr, nullptr, CN1, 0.f, 0, 0);
    pass_row_k<<<gC, blk, 0, stream>>>(RM_CONV, A, V1);
    pass_col_k<<<gC, blk, 0, stream>>>(CM_EXTRACT, nullptr, 0, A, nullptr,
                                       nullptr, Hc, nullptr, CN1, 0.f, 0, 0);

    // X path + combine + inverse-chirp transform
    pass_col_k<<<gC, blk, 0, stream>>>(CM_REAL, xq, XLEN, nullptr, nullptr,
                                       A, nullptr, nullptr, CN1, 0.f, 0, 0);
    pass_row_k<<<gC, blk, 0, stream>>>(RM_CONV, A, V1);
    pass_col_k<<<gC, blk, 0, stream>>>(CM_COMBINE, nullptr, 0, A, Hc,
                                       A, nullptr, nullptr, CN2, 0.f, 0, 0);
    pass_row_k<<<gC, blk, 0, stream>>>(RM_CONV, A, W);
    pass_col_k<<<gC, blk, 0, stream>>>(CM_FINAL, nullptr, 0, A, nullptr,
                                       nullptr, nullptr, oq, CN2, 0.f, 0, 0);
  }
}

// Round 5
// 1317.168 us; speedup vs baseline: 1.4851x; 1.0118x over previous
//
#include <hip/hip_runtime.h>
#include <hip/hip_fp16.h>

// Literal replication of the reference:
//   X = rfft(x, n=163839); H = rfft(h, n=163839); y = irfft(X*H)[:131072]
// N1=163839, N2=163838 -> Bluestein on L=2^18; four-step 512x512.
// R3: register+shuffle FFT-512, LDS only for layout conversion, row passes LDS-free.
// R4: all trig in TURNS via native v_sin/v_cos (revolutions semantics);
//     COMBINE chirp pair collapsed via N1-N2=1 -> e^{+i pi k^2/(N1 N2)}, no mod.

#define L1FFT 262144
#define NCHAN 128
#define CN1 163839LL
#define CN2 163838LL
#define MBINS 81920
#define XLEN 131072
#define HLEN 32768
#define TWO_PI 6.28318530717958647692f
#define INV512T (1.0f/512.0f)
#define INVLT   (1.0f/262144.0f)
#define CHIRP12 ((float)(0.5 / (163839.0 * 163838.0)))   // turns per k^2

#define CM_BUILD   0
#define CM_REAL    1
#define CM_COMBINE 2
#define CM_EXTRACT 3
#define CM_FINAL   4
#define RM_BUILD   0
#define RM_CONV    1

#define TSTRIDE 514   // float2 tile row stride (bank-floor maps)

__device__ __forceinline__ float2 cmulf(float2 a, float2 b) {
  return make_float2(a.x*b.x - a.y*b.y, a.x*b.y + a.y*b.x);
}
__device__ __forceinline__ float2 caddf(float2 a, float2 b){ return make_float2(a.x+b.x, a.y+b.y); }
__device__ __forceinline__ float2 csubf(float2 a, float2 b){ return make_float2(a.x-b.x, a.y-b.y); }

// e^{i*2pi*t}, |t| < 1 — native HW sin/cos take revolutions (v_sin_f32: sin(S0*2pi))
__device__ __forceinline__ float2 sc_turn(float t) {
  return make_float2(__builtin_amdgcn_cosf(t), __builtin_amdgcn_sinf(t));
}

// e^{sgn*i*pi*n^2/N1}: exact int64 mod by compile-time 2*N1, then turns
__device__ __forceinline__ float2 chirp1(float sgn, long long n) {
  long long m = (n*n) % (2*CN1);
  return sc_turn(sgn * (float)m * (1.0f/(float)(2*CN1)));
}
// e^{sgn*i*pi*n^2/N2}
__device__ __forceinline__ float2 chirp2(float sgn, long long n) {
  long long m = (n*n) % (2*CN2);
  return sc_turn(sgn * (float)m * (1.0f/(float)(2*CN2)));
}
// generic (runtime Q) — only used by the tiny BUILD dispatches
__device__ __forceinline__ float2 chirpv(float sgn, long long Q, long long n) {
  long long m = (n*n) % (2*Q);
  float ang = sgn * (0.5f*TWO_PI) * (float)m / (float)Q;
  float s, c; __sincosf(ang, &s, &c);
  return make_float2(c, s);
}

__device__ __forceinline__ int brev4(int x) {
  return ((x&1)<<3) | ((x&2)<<1) | ((x&4)>>1) | ((x&8)>>3);
}
__device__ __forceinline__ int brev5(int x) {
  return (int)(__brev((unsigned)x) >> 27);
}
__device__ __forceinline__ float2 shflx(float2 a, int m) {
  return make_float2(__shfl_xor(a.x, m, 64), __shfl_xor(a.y, m, 64));
}

#define C16_1 0.9238795325f
#define C16_2 0.7071067812f
#define C16_3 0.3826834324f
__device__ __forceinline__ float c16t(int j) {
  const float C[8] = {1.f, C16_1, C16_2, C16_3, 0.f, -C16_3, -C16_2, -C16_1};
  return C[j];
}
__device__ __forceinline__ float s16t(int j) {
  const float S[8] = {0.f, C16_3, C16_2, C16_1, 1.f, C16_1, C16_2, C16_3};
  return S[j];
}

// ---- in-lane 16-point DIF (forward, sign dsg): v[p] ends as F[brev4(p)] ----
__device__ __forceinline__ void lane16_fwd(float2 v[16], float dsg) {
  #pragma unroll
  for (int j = 0; j < 8; ++j) {
    float wr = c16t(j), wi = dsg * s16t(j);
    float2 a = v[j], b = v[j+8];
    v[j] = caddf(a, b);
    float2 tt = csubf(a, b);
    v[j+8] = make_float2(tt.x*wr - tt.y*wi, tt.x*wi + tt.y*wr);
  }
  #pragma unroll
  for (int h = 0; h < 2; ++h)
    #pragma unroll
    for (int j = 0; j < 4; ++j) {
      int i0 = h*8 + j;
      float wr = c16t(2*j), wi = dsg * s16t(2*j);
      float2 a = v[i0], b = v[i0+4];
      v[i0] = caddf(a, b);
      float2 tt = csubf(a, b);
      v[i0+4] = make_float2(tt.x*wr - tt.y*wi, tt.x*wi + tt.y*wr);
    }
  #pragma unroll
  for (int q = 0; q < 4; ++q)
    #pragma unroll
    for (int j = 0; j < 2; ++j) {
      int i0 = q*4 + j;
      float2 a = v[i0], b = v[i0+2];
      v[i0] = caddf(a, b);
      float2 tt = csubf(a, b);
      v[i0+2] = (j == 0) ? tt : make_float2(-dsg*tt.y, dsg*tt.x);
    }
  #pragma unroll
  for (int p = 0; p < 8; ++p) {
    float2 a = v[2*p], b = v[2*p+1];
    v[2*p] = caddf(a, b);
    v[2*p+1] = csubf(a, b);
  }
}

// ---- in-lane 16-point inverse-mirror ----
__device__ __forceinline__ void lane16_inv(float2 v[16], float dsg) {
  #pragma unroll
  for (int p = 0; p < 8; ++p) {
    float2 a = v[2*p], b = v[2*p+1];
    v[2*p] = caddf(a, b);
    v[2*p+1] = csubf(a, b);
  }
  #pragma unroll
  for (int q = 0; q < 4; ++q)
    #pragma unroll
    for (int j = 0; j < 2; ++j) {
      int i0 = q*4 + j;
      float2 a = v[i0], b = v[i0+2];
      float2 tb = (j == 0) ? b : make_float2(dsg*b.y, -dsg*b.x);
      v[i0] = caddf(a, tb);
      v[i0+2] = csubf(a, tb);
    }
  #pragma unroll
  for (int h = 0; h < 2; ++h)
    #pragma unroll
    for (int j = 0; j < 4; ++j) {
      int i0 = h*8 + j;
      float wr = c16t(2*j), wi = dsg * s16t(2*j);
      float2 a = v[i0], b = v[i0+4];
      float2 tb = make_float2(b.x*wr + b.y*wi, b.y*wr - b.x*wi);
      v[i0] = caddf(a, tb);
      v[i0+4] = csubf(a, tb);
    }
  #pragma unroll
  for (int j = 0; j < 8; ++j) {
    float wr = c16t(j), wi = dsg * s16t(j);
    float2 a = v[j], b = v[j+8];
    float2 tb = make_float2(b.x*wr + b.y*wi, b.y*wr - b.x*wi);
    v[j] = caddf(a, tb);
    v[j+8] = csubf(a, tb);
  }
}

// ---- cross-lane 32-point DIF over lanes (within 32-lane half-wave) ----
#define XFWD_STAGE(mask, w) {                                                  \
    bool hi = (l & (mask)) != 0;                                               \
    _Pragma("unroll")                                                          \
    for (int r = 0; r < 16; ++r) {                                             \
      float2 o = shflx(v[r], (mask));                                          \
      float2 d = hi ? csubf(o, v[r]) : caddf(v[r], o);                         \
      v[r] = hi ? cmulf(d, (w)) : d;                                           \
    } }
#define XFWD_PLAIN(mask) {                                                     \
    bool hi = (l & (mask)) != 0;                                               \
    _Pragma("unroll")                                                          \
    for (int r = 0; r < 16; ++r) {                                             \
      float2 o = shflx(v[r], (mask));                                          \
      v[r] = hi ? csubf(o, v[r]) : caddf(v[r], o);                             \
    } }
#define XINV_STAGE(mask, w) {                                                  \
    bool hi = (l & (mask)) != 0;                                               \
    _Pragma("unroll")                                                          \
    for (int r = 0; r < 16; ++r) {                                             \
      float2 b = hi ? make_float2(v[r].x*(w).x + v[r].y*(w).y,                 \
                                  v[r].y*(w).x - v[r].x*(w).y) : v[r];         \
      float2 o = shflx(b, (mask));                                             \
      v[r] = hi ? csubf(o, b) : caddf(b, o);                                   \
    } }
#define XINV_PLAIN(mask) {                                                     \
    bool hi = (l & (mask)) != 0;                                               \
    _Pragma("unroll")                                                          \
    for (int r = 0; r < 16; ++r) {                                             \
      float2 b = v[r];                                                         \
      float2 o = shflx(b, (mask));                                             \
      v[r] = hi ? csubf(o, b) : caddf(b, o);                                   \
    } }

// Full 512-pt forward: input lane l reg m = x[l+32m];
// output lane l reg r = X[brev4(r) + 16*brev5(l)].
__device__ __forceinline__ void fft512_fwd(float2 v[16], int l, float dsg) {
  lane16_fwd(v, dsg);
  #pragma unroll
  for (int r = 1; r < 16; ++r)                // W512^{l*brev4(r)} — exact turns
    v[r] = cmulf(v[r], sc_turn(dsg * INV512T * (float)(l * brev4(r))));
  float2 wA = sc_turn(dsg * (1.0f/32.0f) * (float)(l & 15));
  float2 wB = sc_turn(dsg * (1.0f/16.0f) * (float)(l & 7));
  float2 wC = sc_turn(dsg * (1.0f/8.0f)  * (float)(l & 3));
  float2 wD = (l&1) ? make_float2(0.f, dsg) : make_float2(1.f, 0.f);
  XFWD_STAGE(16, wA); XFWD_STAGE(8, wB); XFWD_STAGE(4, wC);
  XFWD_STAGE(2, wD);  XFWD_PLAIN(1);
}

// Unnormalized inverse (x512) of fft512_fwd(dsg)
__device__ __forceinline__ void fft512_inv(float2 v[16], int l, float dsg) {
  float2 wA = sc_turn(dsg * (1.0f/32.0f) * (float)(l & 15));
  float2 wB = sc_turn(dsg * (1.0f/16.0f) * (float)(l & 7));
  float2 wC = sc_turn(dsg * (1.0f/8.0f)  * (float)(l & 3));
  float2 wD = (l&1) ? make_float2(0.f, dsg) : make_float2(1.f, 0.f);
  XINV_PLAIN(1); XINV_STAGE(2, wD); XINV_STAGE(4, wC);
  XINV_STAGE(8, wB); XINV_STAGE(16, wA);
  #pragma unroll
  for (int r = 1; r < 16; ++r)
    v[r] = cmulf(v[r], sc_turn(-dsg * INV512T * (float)(l * brev4(r))));
  lane16_inv(v, dsg);
}

// ---------------- column pass ----------------
__global__ __launch_bounds__(256) void pass_col_k(
    int mode,
    const float* __restrict__ realSrc, int realLen,
    const float2* cplxSrc,
    const __half2* __restrict__ hcIn,
    float2* dstFull,
    __half2* __restrict__ specOut,
    float* __restrict__ realOut,
    long long Q, float csgn, int lo, int hi)
{
  __shared__ float2 tile[8 * TSTRIDE];
  const int t   = threadIdx.x;
  const int c0  = blockIdx.x * 8;
  const int ch  = blockIdx.y;
  const int l   = t & 31;
  const int ccf = t >> 5;
  const int c   = c0 + ccf;
  float2 v[16];

  if (mode == CM_BUILD) {
    #pragma unroll
    for (int m = 0; m < 16; ++m) {
      int n = ((l + 32*m) << 9) + c;
      int np = (n <= hi) ? n : n - L1FFT;
      v[m] = (np >= lo) ? chirpv(csgn, Q, (long long)np) : make_float2(0.f, 0.f);
    }
  } else if (mode == CM_REAL) {
    #pragma unroll
    for (int i = 0; i < 16; ++i) {
      int qq = t + 256*i;
      int cc = qq & 7, r = qq >> 3;
      int n = (r << 9) + c0 + cc;
      float2 val = make_float2(0.f, 0.f);
      if (n < realLen) {
        float xv = realSrc[(size_t)ch * realLen + n];
        float2 cw = chirp1(-1.f, (long long)n);        // pre-chirp
        val = make_float2(xv*cw.x, xv*cw.y);
      }
      tile[cc*TSTRIDE + r] = val;
    }
    __syncthreads();
    #pragma unroll
    for (int m = 0; m < 16; ++m) v[m] = tile[ccf*TSTRIDE + l + 32*m];
    __syncthreads();
  } else {
    #pragma unroll
    for (int i = 0; i < 16; ++i) {
      int qq = t + 256*i;
      int cc = qq & 7, z = qq >> 3;
      int la = z & 31, ra = z >> 5;
      int j = brev4(ra) + 16*brev5(la);
      tile[cc*TSTRIDE + la + 32*ra] = cplxSrc[(size_t)ch*L1FFT + (j << 9) + c0 + cc];
    }
    __syncthreads();
    #pragma unroll
    for (int m = 0; m < 16; ++m) v[m] = tile[ccf*TSTRIDE + l + 32*m];
    __syncthreads();
  }

  if (mode == CM_COMBINE) {
    fft512_inv(v, l, -1.f);         // completes X's Bluestein conv
    #pragma unroll
    for (int m = 0; m < 16; ++m) {
      if (m <= 4) {                 // n < 160 <=> k < MBINS
        int n = l + 32*m;
        long long k = ((long long)n << 9) + c;
        // postchirp1*prechirp2 = e^{+i pi k^2/(N1*N2)} (N1-N2=1); no mod needed
        float fk = (float)k;
        float2 w = sc_turn(fk * fk * CHIRP12);
        float2 H = __half22float2(hcIn[(size_t)ch*MBINS + c*160 + n]);
        float2 Y = cmulf(v[m], H);
        float eps = (k == 0 || k == MBINS-1) ? 1.f : 2.f;
        float sc = eps / (float)CN2;
        v[m] = cmulf(make_float2(Y.x*sc, Y.y*sc), w);
      } else v[m] = make_float2(0.f, 0.f);
    }
  }

  if (mode <= CM_COMBINE) {         // BUILD / REAL / COMBINE: fwd FFT + store
    fft512_fwd(v, l, -1.f);
    #pragma unroll
    for (int r = 0; r < 16; ++r) {  // four-step twiddle (exact turns) + slot write
      int k1 = brev4(r), k2 = brev5(l);
      int kf = k1 + 16*k2;
      float2 w = sc_turn(-INVLT * (float)(c * kf));
      tile[ccf*TSTRIDE + k2 + 32*k1] = cmulf(v[r], w);
    }
    __syncthreads();
    {
      int cc = t & 7, u = t >> 3;
      #pragma unroll
      for (int i = 0; i < 16; ++i)
        dstFull[(size_t)ch*L1FFT + ((i + 16*u) << 9) + c0 + cc] =
            tile[cc*TSTRIDE + u + 32*i];
    }
  } else if (mode == CM_EXTRACT) {
    fft512_inv(v, l, -1.f);
    #pragma unroll
    for (int m = 0; m <= 4; ++m) {
      int n = l + 32*m;
      long long k = ((long long)n << 9) + c;
      float2 cw = chirp1(-1.f, k);
      specOut[(size_t)ch*MBINS + c*160 + n] = __float22half2_rn(cmulf(v[m], cw));
    }
  } else {                          // CM_FINAL
    fft512_inv(v, l, -1.f);
    float* tf = (float*)tile;
    #pragma unroll
    for (int m = 0; m < 8; ++m) {
      int n = l + 32*m;
      long long nb = ((long long)n << 9) + c;
      float2 cw = chirp2(+1.f, nb);
      tf[ccf*513 + n] = v[m].x*cw.x - v[m].y*cw.y;
    }
    __syncthreads();
    {
      int cc = t & 7, u = t >> 3;
      #pragma unroll
      for (int i = 0; i < 8; ++i) {
        int n = u + 32*i;
        realOut[(size_t)ch*XLEN + (n << 9) + c0 + cc] = tf[cc*513 + n];
      }
    }
  }
}

// ---------------- row pass (LDS-free) ----------------
__global__ __launch_bounds__(256) void pass_row_k(
    int mode, float2* a, const float2* __restrict__ g)
{
  const int t = threadIdx.x;
  const int l = t & 31;
  const int row = blockIdx.x * 8 + (t >> 5);
  const int ch = blockIdx.y;
  float2* A = a + (size_t)ch * L1FFT + (size_t)row * 512;
  float2 v[16];
  #pragma unroll
  for (int m = 0; m < 16; ++m) v[m] = A[l + 32*m];

  if (mode == RM_CONV) {
    const float2* G = g + (size_t)row * 512;
    float2 gv[16];
    #pragma unroll
    for (int m = 0; m < 16; ++m) gv[m] = G[l + 32*m];
    fft512_fwd(v, l, -1.f);
    #pragma unroll
    for (int r = 0; r < 16; ++r) v[r] = cmulf(v[r], gv[r]);
    fft512_inv(v, l, -1.f);
    #pragma unroll
    for (int m = 0; m < 16; ++m) {
      int cidx = l + 32*m;
      float2 w = sc_turn(INVLT * (float)(cidx * row));   // conj four-step twiddle
      float2 r_ = cmulf(v[m], w);
      A[cidx] = make_float2(r_.x * (1.f/(float)L1FFT), r_.y * (1.f/(float)L1FFT));
    }
  } else {
    fft512_fwd(v, l, -1.f);
    #pragma unroll
    for (int r = 0; r < 16; ++r) A[l + 32*r] = v[r];  // FFT-state order
  }
}

__global__ void diag_ws_too_small(float* out) { out[0] = 123456.0f; }

extern "C" void kernel_launch(void* const* d_in, const int* in_sizes, int n_in,
                              void* d_out, int out_size, void* d_ws, size_t ws_size,
                              hipStream_t stream) {
  const float* x = (const float*)d_in[0];   // (32,4,131072) f32
  const float* h = (const float*)d_in[1];   // (32,4,32768)  f32
  float* out = (float*)d_out;

  const size_t fixedB   = 2ull * L1FFT * sizeof(float2);
  const size_t perChanB = (size_t)L1FFT * sizeof(float2) + (size_t)MBINS * sizeof(__half2);
  if (ws_size < fixedB + perChanB) {
    diag_ws_too_small<<<1, 1, 0, stream>>>(out);
    return;
  }
  int chunk = (int)((ws_size - fixedB) / perChanB);
  if (chunk > NCHAN) chunk = NCHAN;

  float2*  V1 = (float2*)d_ws;
  float2*  W  = V1 + L1FFT;
  float2*  A  = W + L1FFT;
  __half2* Hc = (__half2*)(A + (size_t)chunk * L1FFT);

  dim3 blk(256);
  dim3 g1(64, 1);

  // chirp-kernel spectra (channel-independent)
  pass_col_k<<<g1, blk, 0, stream>>>(CM_BUILD, nullptr, 0, nullptr, nullptr,
                                     V1, nullptr, nullptr, CN1, +1.f, -(XLEN-1), MBINS-1);
  pass_row_k<<<g1, blk, 0, stream>>>(RM_BUILD, V1, nullptr);
  pass_col_k<<<g1, blk, 0, stream>>>(CM_BUILD, nullptr, 0, nullptr, nullptr,
                                     W, nullptr, nullptr, CN2, -1.f, -(MBINS-1), XLEN-1);
  pass_row_k<<<g1, blk, 0, stream>>>(RM_BUILD, W, nullptr);

  for (int ch0 = 0; ch0 < NCHAN; ch0 += chunk) {
    int nc = NCHAN - ch0; if (nc > chunk) nc = chunk;
    dim3 gC(64, nc);
    const float* hq = h   + (size_t)ch0 * HLEN;
    const float* xq = x   + (size_t)ch0 * XLEN;
    float*       oq = out + (size_t)ch0 * XLEN;

    // H[k] -> Hc ([c][n] layout, half2, postchirp applied)
    pass_col_k<<<gC, blk, 0, stream>>>(CM_REAL, hq, HLEN, nullptr, nullptr,
                                       A, nullptr, nullptr, CN1, 0.f, 0, 0);
    pass_row_k<<<gC, blk, 0, stream>>>(RM_CONV, A, V1);
    pass_col_k<<<gC, blk, 0, stream>>>(CM_EXTRACT, nullptr, 0, A, nullptr,
                                       nullptr, Hc, nullptr, CN1, 0.f, 0, 0);

    // X path + combine + inverse-chirp transform
    pass_col_k<<<gC, blk, 0, stream>>>(CM_REAL, xq, XLEN, nullptr, nullptr,
                                       A, nullptr, nullptr, CN1, 0.f, 0, 0);
    pass_row_k<<<gC, blk, 0, stream>>>(RM_CONV, A, V1);
    pass_col_k<<<gC, blk, 0, stream>>>(CM_COMBINE, nullptr, 0, A, Hc,
                                       A, nullptr, nullptr, CN2, 0.f, 0, 0);
    pass_row_k<<<gC, blk, 0, stream>>>(RM_CONV, A, W);
    pass_col_k<<<gC, blk, 0, stream>>>(CM_FINAL, nullptr, 0, A, nullptr,
                                       nullptr, nullptr, oq, CN2, 0.f, 0, 0);
  }
}